// Round 7
// baseline (368.032 us; speedup 1.0000x reference)
//
#include <hip/hip_runtime.h>

#define CONC_N 2000
#define ITEM_N 20000
#define STU_N  50000
#define NE_CC  40000
#define NE_IC  80000
#define NE_SI  1000000
#define TBUCK  382   // 63+63+79+79+98

typedef unsigned int uint;
typedef unsigned short ushort;
typedef __attribute__((ext_vector_type(8))) short bf16x8;
typedef __attribute__((ext_vector_type(4))) float f32x4;

__device__ __forceinline__ ushort f2bf(float f) {
  uint u = __float_as_uint(f);
  uint r = (u + 0x7FFFu + ((u >> 16) & 1u)) >> 16;
  return (ushort)r;
}

__device__ __forceinline__ bf16x8 packfrag(float4 lo, float4 hi) {
  union { bf16x8 s; uint u[4]; } p;
  p.u[0] = (uint)f2bf(lo.x) | ((uint)f2bf(lo.y) << 16);
  p.u[1] = (uint)f2bf(lo.z) | ((uint)f2bf(lo.w) << 16);
  p.u[2] = (uint)f2bf(hi.x) | ((uint)f2bf(hi.y) << 16);
  p.u[3] = (uint)f2bf(hi.z) | ((uint)f2bf(hi.w) << 16);
  return p.s;
}

// ---------------- CSR structures ----------------

struct CsrG {
  const int* dst; const int* src;
  unsigned* keys; int* srcs; int* offs;
  int E, n, shift, nbuck, tb, sb;
};
struct CsrGs { CsrG g[5]; };

// ---------------- setup: proj vectors + CSR histograms + W->bf16 ----------

struct ProjDesc { const float* W; const float* a; float* out; };
struct SetupArgs {
  ProjDesc p[10];
  CsrGs G;
  int* pcnt;                 // [5*32][128]
  const float* wsrc[5];
  ushort* wdst[5];
};

__global__ __launch_bounds__(256) void setup_k(SetupArgs A) {
  int b = blockIdx.x;
  int tid = threadIdx.x;
  if (b < 10) {
    if (tid < 128) {
      ProjDesc d = A.p[b];
      float acc = 0.f;
      for (int j = 0; j < 128; ++j) acc += d.W[j * 128 + tid] * d.a[j];
      d.out[tid] = acc;
    }
    return;
  }
  if (b >= 170) {            // W fp32 -> bf16 tables
    int wi = b - 170;
    const float* Ws = A.wsrc[wi];
    ushort* Wd = A.wdst[wi];
    #pragma unroll
    for (int i = 0; i < 16; ++i) {
      int s = tid + i * 256;           // float4 index 0..4095
      float4 v = *(const float4*)&Ws[s * 4];
      ushort4 o;
      o.x = f2bf(v.x); o.y = f2bf(v.y); o.z = f2bf(v.z); o.w = f2bf(v.w);
      *(ushort4*)&Wd[s * 4] = o;
    }
    return;
  }
  int bsel = b - 10;            // 0..159
  int gi = bsel >> 5, blk = bsel & 31;
  CsrG g = A.G.g[gi];
  __shared__ int lcnt[128];
  if (tid < 128) lcnt[tid] = 0;
  __syncthreads();
  int chunk = (g.E + 31) >> 5;
  int e0 = blk * chunk, e1 = min(g.E, e0 + chunk);
  for (int e = e0 + tid; e < e1; e += 256)
    atomicAdd(&lcnt[g.dst[e] >> g.shift], 1);
  __syncthreads();
  if (tid < 128) A.pcnt[bsel * 128 + tid] = lcnt[tid];
}

// ---------------- CSR scan / partition / build ----------------

__global__ __launch_bounds__(512) void csr_scan(CsrGs G, const int* __restrict__ pcnt,
                                                int* __restrict__ cur, int* __restrict__ bases) {
  __shared__ int lc[TBUCK];
  __shared__ int lb[TBUCK + 5];
  int tid = threadIdx.x;
  if (tid < TBUCK) {
    int gi = 0;
    #pragma unroll
    for (int k = 1; k < 5; ++k) if (tid >= G.g[k].tb) gi = k;
    int b = tid - G.g[gi].tb;
    int s = 0;
    for (int blk = 0; blk < 32; ++blk) s += pcnt[((gi << 5) + blk) * 128 + b];
    lc[tid] = s;
  }
  __syncthreads();
  if (tid == 0) {
    for (int gi = 0; gi < 5; ++gi) {
      CsrG g = G.g[gi];
      int run = 0;
      for (int b = 0; b < g.nbuck; ++b) { lb[g.sb + b] = run; run += lc[g.tb + b]; }
      lb[g.sb + g.nbuck] = run;
    }
  }
  __syncthreads();
  if (tid < TBUCK + 5) bases[tid] = lb[tid];
  if (tid < TBUCK) {
    int gi = 0;
    for (int k = 1; k < 5; ++k) if (tid >= G.g[k].tb) gi = k;
    cur[tid] = lb[tid + gi];
  }
  if (tid < 5) G.g[tid].offs[G.g[tid].n] = G.g[tid].E;
}

__global__ __launch_bounds__(256) void csr_partition(CsrGs G, int* __restrict__ cur) {
  CsrG g = G.g[blockIdx.y];
  __shared__ unsigned ck[4096];
  __shared__ unsigned char cb[4096];
  __shared__ int lcnt[128], lcur[128];
  int tid = threadIdx.x;
  unsigned dmask = (1u << g.shift) - 1;
  for (int c0 = blockIdx.x * 4096; c0 < g.E; c0 += gridDim.x * 4096) {
    if (tid < 128) lcnt[tid] = 0;
    __syncthreads();
    #pragma unroll
    for (int i = 0; i < 16; ++i) {
      int e = c0 + i * 256 + tid;
      if (e < g.E) {
        int d = g.dst[e], s = g.src[e];
        int b = d >> g.shift;
        ck[i * 256 + tid] = ((unsigned)(d & dmask) << 16) | (unsigned)s;
        cb[i * 256 + tid] = (unsigned char)b;
        atomicAdd(&lcnt[b], 1);
      } else cb[i * 256 + tid] = 255;
    }
    __syncthreads();
    if (tid < g.nbuck && lcnt[tid] > 0) lcur[tid] = atomicAdd(&cur[g.tb + tid], lcnt[tid]);
    __syncthreads();
    #pragma unroll
    for (int i = 0; i < 16; ++i) {
      int b = cb[i * 256 + tid];
      if (b != 255) {
        int pos = atomicAdd(&lcur[b], 1);
        g.keys[pos] = ck[i * 256 + tid];
      }
    }
    __syncthreads();
  }
}

__global__ __launch_bounds__(256) void csr_build(CsrGs G, const int* __restrict__ bases) {
  int bid = blockIdx.x;
  int gi = 0;
  for (int k = 1; k < 5; ++k) if (bid >= G.g[k].tb) gi = k;
  CsrG g = G.g[gi];
  int b = bid - g.tb;
  int base = bases[g.sb + b];
  int cnt = bases[g.sb + b + 1] - base;
  if (cnt > 16384) cnt = 16384;

  __shared__ unsigned lkeys[16384];
  __shared__ int lh[512], lex[512], lcu[512], wsum[4];
  int tid = threadIdx.x;
  lh[tid] = 0; lh[tid + 256] = 0;
  __syncthreads();
  for (int j = tid; j < cnt; j += 256) {
    unsigned k = g.keys[base + j];
    lkeys[j] = k;
    atomicAdd(&lh[k >> 16], 1);
  }
  __syncthreads();
  int a0 = lh[2 * tid], a1 = lh[2 * tid + 1];
  int pair = a0 + a1;
  int lane = tid & 63, wv = tid >> 6;
  int incl = pair;
  #pragma unroll
  for (int o = 1; o < 64; o <<= 1) {
    int y = __shfl_up(incl, o);
    if (lane >= o) incl += y;
  }
  if (lane == 63) wsum[wv] = incl;
  __syncthreads();
  if (tid == 0) {
    int s = 0;
    #pragma unroll
    for (int w = 0; w < 4; ++w) { int t = wsum[w]; wsum[w] = s; s += t; }
  }
  __syncthreads();
  int ep = wsum[wv] + incl - pair;
  lex[2 * tid] = ep;       lex[2 * tid + 1] = ep + a0;
  lcu[2 * tid] = ep;       lcu[2 * tid + 1] = ep + a0;
  __syncthreads();
  int dst0 = b << g.shift;
  int ndst = min(1 << g.shift, g.n - dst0);
  for (int dl = tid; dl < ndst; dl += 256) g.offs[dst0 + dl] = base + lex[dl];
  for (int j = tid; j < cnt; j += 256) {
    unsigned k = lkeys[j];
    int dl = k >> 16;
    int pos = atomicAdd(&lcu[dl], 1);
    g.srcs[base + pos] = (int)(k & 0xFFFFu);
  }
}

// ---------------- batched MFMA GEMM + multi-dot compute ----------------

struct GemmDesc { const float* X; ushort* Y; int n, b0; };
struct MDotDesc { const float* x; const float* v[6]; float* o[6]; int n, nv, b0, nb; };
struct BigC {
  GemmDesc g[5];
  MDotDesc m[4];
  int gemm_blocks;
};

// Y[n,128](bf16) = bf16(X[n,128]) @ bf16(W)[128,128]^T via v_mfma_f32_16x16x32_bf16.
// Fragment layout: lane l -> i/col = l&15; k = kk*32 + {4g+j (j<4), 16+4g+(j-4)}, g=l>>4.
// A frags: coalesced float4 direct from global X. B frags: uint2 pairs from bf16 W table.
__device__ void gemm_body(const float* __restrict__ X, const ushort* __restrict__ Wb,
                          ushort* __restrict__ Y, int n, int blk) {
  int tid = threadIdx.x;
  int lane = tid & 63, wv = tid >> 6;
  int x = lane & 15, g = lane >> 4;
  int row = blk * 64 + wv * 16 + x;
  const float* xr = &X[(size_t)(row < n ? row : 0) * 128];
  bf16x8 afrag[4];
  #pragma unroll
  for (int kk = 0; kk < 4; ++kk) {
    float4 lo = *(const float4*)&xr[kk * 32 + 4 * g];
    float4 hi = *(const float4*)&xr[kk * 32 + 16 + 4 * g];
    afrag[kk] = packfrag(lo, hi);
  }
  f32x4 acc[8];
  #pragma unroll
  for (int t = 0; t < 8; ++t) acc[t] = (f32x4){0.f, 0.f, 0.f, 0.f};
  #pragma unroll
  for (int nt = 0; nt < 8; ++nt) {
    const ushort* wc = &Wb[(size_t)(nt * 16 + x) * 128];
    #pragma unroll
    for (int kk = 0; kk < 4; ++kk) {
      uint2 lo = *(const uint2*)&wc[kk * 32 + 4 * g];
      uint2 hi = *(const uint2*)&wc[kk * 32 + 16 + 4 * g];
      union { uint4 u; bf16x8 s; } bu;
      bu.u = make_uint4(lo.x, lo.y, hi.x, hi.y);
      acc[nt] = __builtin_amdgcn_mfma_f32_16x16x32_bf16(afrag[kk], bu.s, acc[nt], 0, 0, 0);
    }
  }
  // D layout: col = lane&15, row = (lane>>4)*4 + r
  int orow = blk * 64 + wv * 16 + 4 * g;
  #pragma unroll
  for (int r = 0; r < 4; ++r) {
    int gr = orow + r;
    if (gr < n) {
      #pragma unroll
      for (int nt = 0; nt < 8; ++nt)
        Y[(size_t)gr * 128 + nt * 16 + x] = f2bf(acc[nt][r]);
    }
  }
}

__device__ void mdot_body(const MDotDesc& d, int blk) {
  int lane = threadIdx.x & 63;
  int wid = (blk * 256 + threadIdx.x) >> 6;
  int nw = d.nb * 4;
  float va[6], vb[6];
  #pragma unroll
  for (int j = 0; j < 6; ++j) {
    va[j] = (j < d.nv) ? d.v[j][lane] : 0.f;
    vb[j] = (j < d.nv) ? d.v[j][64 + lane] : 0.f;
  }
  for (int r = wid; r < d.n; r += nw) {
    float x0 = d.x[r * 128 + lane], x1 = d.x[r * 128 + 64 + lane];
    #pragma unroll
    for (int j = 0; j < 6; ++j) {
      if (j < d.nv) {
        float a = x0 * va[j] + x1 * vb[j];
        #pragma unroll
        for (int o = 32; o; o >>= 1) a += __shfl_xor(a, o);
        if (lane == 0) d.o[j][r] = a;
      }
    }
  }
}

__global__ __launch_bounds__(256, 3) void big_compute(BigC C, const ushort* W0,
                                                      const ushort* W1, const ushort* W2,
                                                      const ushort* W3, const ushort* W4) {
  int b = blockIdx.x;
  if (b < C.gemm_blocks) {
    int gi = 0;
    #pragma unroll
    for (int k = 1; k < 5; ++k) if (b >= C.g[k].b0) gi = k;
    const ushort* W = (gi == 0) ? W0 : (gi == 1) ? W1 : (gi == 2) ? W2 : (gi == 3) ? W3 : W4;
    gemm_body(C.g[gi].X, W, C.g[gi].Y, C.g[gi].n, b - C.g[gi].b0);
  } else {
    int mi = 0;
    #pragma unroll
    for (int k = 1; k < 4; ++k) if (b >= C.m[k].b0) mi = k;
    mdot_body(C.m[mi], b - C.m[mi].b0);
  }
}

// ---------------- GAT core (wave per target, uint4 bf16 gather) ----------

__device__ void gat_core_bf(const int* __restrict__ offs, const int* __restrict__ srcs,
                            const float* __restrict__ sl, const float* __restrict__ sr,
                            const uint* __restrict__ xl, int t, int lane, float acc[8]) {
  int sbeg = offs[t], send = offs[t + 1];
  float srt = sr[t];
  int i0l = sbeg + lane;
  bool act0 = i0l < send;
  int s0 = act0 ? srcs[i0l] : 0;
  float e0;
  {
    float e = sl[s0] + srt;
    e = e > 0.f ? e : 0.2f * e;
    e0 = act0 ? e : -1e30f;
  }
  float m = e0, se = act0 ? 1.f : 0.f;
  for (int i = i0l + 64; i < send; i += 64) {
    int s = srcs[i];
    float e = sl[s] + srt;
    e = e > 0.f ? e : 0.2f * e;
    float mn = fmaxf(m, e);
    se = se * __expf(m - mn) + __expf(e - mn);
    m = mn;
  }
  #pragma unroll
  for (int o = 32; o; o >>= 1) {
    float m2 = __shfl_xor(m, o), s2 = __shfl_xor(se, o);
    float mn = fmaxf(m, m2);
    se = se * __expf(m - mn) + s2 * __expf(m2 - mn);
    m = mn;
  }
  float inv = 1.f / (se + 1e-16f);

  int g = lane & 15;
  int q = lane >> 4;
  #pragma unroll
  for (int r = 0; r < 8; ++r) acc[r] = 0.f;

  for (int i0 = sbeg; i0 < send; i0 += 64) {
    int cnt = min(64, send - i0);
    int s; float wgt;
    if (i0 == sbeg) {
      s = s0;
      wgt = act0 ? __expf(e0 - m) * inv : 0.f;
    } else {
      s = 0; wgt = 0.f;
      if (lane < cnt) {
        s = srcs[i0 + lane];
        float e = sl[s] + srt;
        e = e > 0.f ? e : 0.2f * e;
        wgt = __expf(e - m) * inv;
      }
    }
    int kmax = (cnt + 3) >> 2;
    #pragma unroll 2
    for (int k = 0; k < kmax; ++k) {
      int ej = 4 * k + q;
      int sj = __shfl(s, ej);
      float wj = __shfl(wgt, ej);
      const uint4 u = *(const uint4*)&xl[(size_t)sj * 64 + g * 4];
      acc[0] += wj * __uint_as_float(u.x << 16);
      acc[1] += wj * __uint_as_float(u.x & 0xFFFF0000u);
      acc[2] += wj * __uint_as_float(u.y << 16);
      acc[3] += wj * __uint_as_float(u.y & 0xFFFF0000u);
      acc[4] += wj * __uint_as_float(u.z << 16);
      acc[5] += wj * __uint_as_float(u.z & 0xFFFF0000u);
      acc[6] += wj * __uint_as_float(u.w << 16);
      acc[7] += wj * __uint_as_float(u.w & 0xFFFF0000u);
    }
  }
  #pragma unroll
  for (int r = 0; r < 8; ++r) {
    acc[r] += __shfl_xor(acc[r], 16);
    acc[r] += __shfl_xor(acc[r], 32);
  }
}

__global__ void gat_agg_bf(const int* __restrict__ offs, const int* __restrict__ srcs,
                           const float* __restrict__ sl, const float* __restrict__ sr,
                           const uint* __restrict__ xl,
                           const float* __restrict__ base0,
                           float* __restrict__ out, int n_tgt) {
  int t = (blockIdx.x * blockDim.x + threadIdx.x) >> 6;
  if (t >= n_tgt) return;
  int lane = threadIdx.x & 63;
  float acc[8];
  gat_core_bf(offs, srcs, sl, sr, xl, t, lane, acc);
  int g = lane & 15;
  if (lane < 16) {
    int d = t * 128 + g * 8;
    float4 a0 = make_float4(acc[0], acc[1], acc[2], acc[3]);
    float4 a1 = make_float4(acc[4], acc[5], acc[6], acc[7]);
    if (base0) {
      const float4 b0 = *(const float4*)&base0[d];
      const float4 b1 = *(const float4*)&base0[d + 4];
      a0.x += b0.x; a0.y += b0.y; a0.z += b0.z; a0.w += b0.w;
      a1.x += b1.x; a1.y += b1.y; a1.z += b1.z; a1.w += b1.w;
    }
    *(float4*)&out[d] = a0;
    *(float4*)&out[d + 4] = a1;
  }
}

// c1 + c2 batched (blockIdx.y selects), epilogue dot with al -> sl_out
__global__ void gat_c1c2(const int* __restrict__ offs0, const int* __restrict__ srcs0,
                         const float* __restrict__ sl0, const float* __restrict__ sr0,
                         const uint* __restrict__ xl0, const float* __restrict__ al0,
                         float* __restrict__ o0, float* __restrict__ slo0,
                         const int* __restrict__ offs1, const int* __restrict__ srcs1,
                         const float* __restrict__ sl1, const float* __restrict__ sr1,
                         const uint* __restrict__ xl1, const float* __restrict__ al1,
                         float* __restrict__ o1, float* __restrict__ slo1,
                         int n_tgt) {
  int t = (blockIdx.x * blockDim.x + threadIdx.x) >> 6;
  if (t >= n_tgt) return;
  int lane = threadIdx.x & 63;
  int which = blockIdx.y;
  const int* offs = which ? offs1 : offs0;
  const int* srcs = which ? srcs1 : srcs0;
  const float* sl = which ? sl1 : sl0;
  const float* sr = which ? sr1 : sr0;
  const uint* xl = which ? xl1 : xl0;
  const float* al = which ? al1 : al0;
  float* o = which ? o1 : o0;
  float* slo = which ? slo1 : slo0;

  float acc[8];
  gat_core_bf(offs, srcs, sl, sr, xl, t, lane, acc);
  int g = lane & 15;
  float4 v0 = *(const float4*)&al[g * 8];
  float4 v1 = *(const float4*)&al[g * 8 + 4];
  float p = acc[0] * v0.x + acc[1] * v0.y + acc[2] * v0.z + acc[3] * v0.w +
            acc[4] * v1.x + acc[5] * v1.y + acc[6] * v1.z + acc[7] * v1.w;
  #pragma unroll
  for (int o2 = 8; o2; o2 >>= 1) p += __shfl_xor(p, o2);
  if (lane == 0) slo[t] = p;
  if (lane < 16) {
    int d = t * 128 + g * 8;
    *(float4*)&o[d] = make_float4(acc[0], acc[1], acc[2], acc[3]);
    *(float4*)&o[d + 4] = make_float4(acc[4], acc[5], acc[6], acc[7]);
  }
}

// fp32-gather dual (cc graph, gathers c1buf/c2buf), writes base + r1 + r2
__global__ void gat_agg_dual(const int* __restrict__ offs, const int* __restrict__ srcs,
                             const float* __restrict__ sl1, const float* __restrict__ sr1,
                             const float* __restrict__ xl1,
                             const float* __restrict__ sl2, const float* __restrict__ sr2,
                             const float* __restrict__ xl2,
                             const float* __restrict__ base,
                             float* __restrict__ out, int n_tgt) {
  int t = (blockIdx.x * blockDim.x + threadIdx.x) >> 6;
  if (t >= n_tgt) return;
  int lane = threadIdx.x & 63;
  int sbeg = offs[t], send = offs[t + 1];
  float srt1 = sr1[t], srt2 = sr2[t];
  float m1 = -1e30f, m2 = -1e30f;
  for (int i = sbeg + lane; i < send; i += 64) {
    int s = srcs[i];
    float e1 = sl1[s] + srt1; e1 = e1 > 0.f ? e1 : 0.2f * e1;
    float e2 = sl2[s] + srt2; e2 = e2 > 0.f ? e2 : 0.2f * e2;
    m1 = fmaxf(m1, e1); m2 = fmaxf(m2, e2);
  }
  #pragma unroll
  for (int o = 32; o; o >>= 1) {
    m1 = fmaxf(m1, __shfl_xor(m1, o));
    m2 = fmaxf(m2, __shfl_xor(m2, o));
  }
  float se1 = 0.f, se2 = 0.f;
  for (int i = sbeg + lane; i < send; i += 64) {
    int s = srcs[i];
    float e1 = sl1[s] + srt1; e1 = e1 > 0.f ? e1 : 0.2f * e1;
    float e2 = sl2[s] + srt2; e2 = e2 > 0.f ? e2 : 0.2f * e2;
    se1 += __expf(e1 - m1); se2 += __expf(e2 - m2);
  }
  #pragma unroll
  for (int o = 32; o; o >>= 1) {
    se1 += __shfl_xor(se1, o);
    se2 += __shfl_xor(se2, o);
  }
  float inv1 = 1.f / (se1 + 1e-16f), inv2 = 1.f / (se2 + 1e-16f);
  float ax = 0.f, ay = 0.f;
  for (int i0 = sbeg; i0 < send; i0 += 64) {
    int cnt = min(64, send - i0);
    int s = 0; float w1 = 0.f, w2 = 0.f;
    if (lane < cnt) {
      s = srcs[i0 + lane];
      float e1 = sl1[s] + srt1; e1 = e1 > 0.f ? e1 : 0.2f * e1;
      float e2 = sl2[s] + srt2; e2 = e2 > 0.f ? e2 : 0.2f * e2;
      w1 = __expf(e1 - m1) * inv1;
      w2 = __expf(e2 - m2) * inv2;
    }
    for (int j = 0; j < cnt; ++j) {
      int sj = __shfl(s, j);
      float wj1 = __shfl(w1, j);
      float wj2 = __shfl(w2, j);
      const float2 v1 = *(const float2*)&xl1[sj * 128 + lane * 2];
      const float2 v2 = *(const float2*)&xl2[sj * 128 + lane * 2];
      ax += wj1 * v1.x + wj2 * v2.x;
      ay += wj1 * v1.y + wj2 * v2.y;
    }
  }
  const float2 b = *(const float2*)&base[t * 128 + lane * 2];
  float2 o2; o2.x = ax + b.x; o2.y = ay + b.y;
  *(float2*)&out[t * 128 + lane * 2] = o2;
}

// ---------------- launch ----------------

extern "C" void kernel_launch(void* const* d_in, const int* in_sizes, int n_in,
                              void* d_out, int out_size, void* d_ws, size_t ws_size,
                              hipStream_t stream) {
  const float* stu_x     = (const float*)d_in[0];
  const float* item_x    = (const float*)d_in[1];
  const float* conc_x    = (const float*)d_in[2];
  const float* stu_raw_x = (const float*)d_in[3];
  const float* W_cc  = (const float*)d_in[4];
  const float* al_cc = (const float*)d_in[5];
  const float* ar_cc = (const float*)d_in[6];
  const float* W_ic  = (const float*)d_in[7];
  const float* al_ic = (const float*)d_in[8];
  const float* ar_ic = (const float*)d_in[9];
  const float* al_cce = (const float*)d_in[10];
  const float* ar_cce = (const float*)d_in[11];
  const float* al_ice = (const float*)d_in[12];
  const float* ar_ice = (const float*)d_in[13];
  const float* W_ci  = (const float*)d_in[14];
  const float* al_ci = (const float*)d_in[15];
  const float* ar_ci = (const float*)d_in[16];
  const float* W_si  = (const float*)d_in[17];
  const float* al_si = (const float*)d_in[18];
  const float* ar_si = (const float*)d_in[19];
  const float* W_is  = (const float*)d_in[22];
  const float* al_is = (const float*)d_in[23];
  const float* ar_is = (const float*)d_in[24];
  const int* cc_src  = (const int*)d_in[25];
  const int* cc_dst  = (const int*)d_in[26];
  const int* ic_item = (const int*)d_in[27];
  const int* ic_conc = (const int*)d_in[28];
  const int* si_stu  = (const int*)d_in[29];
  const int* si_item = (const int*)d_in[30];

  char* wsb = (char*)d_ws;
  size_t off = 0;
  auto alloc = [&](size_t bytes) -> void* {
    void* p = wsb + off;
    off = (off + bytes + 255) & ~(size_t)255;
    return p;
  };

  ushort* concWcc = (ushort*)alloc((size_t)CONC_N * 128 * 2);
  ushort* itemWic = (ushort*)alloc((size_t)ITEM_N * 128 * 2);
  ushort* concWci = (ushort*)alloc((size_t)CONC_N * 128 * 2);
  ushort* stuWsi  = (ushort*)alloc((size_t)STU_N  * 128 * 2);
  ushort* itemWis = (ushort*)alloc((size_t)ITEM_N * 128 * 2);
  ushort* Wbf[5];
  for (int i = 0; i < 5; ++i) Wbf[i] = (ushort*)alloc(128 * 128 * 2);
  float* c1buf   = (float*)alloc((size_t)CONC_N * 128 * 4);
  float* c2buf   = (float*)alloc((size_t)CONC_N * 128 * 4);
  float* vecs    = (float*)alloc(10 * 128 * 4);
  float* sl_cc  = (float*)alloc(CONC_N * 4);
  float* sr_cc  = (float*)alloc(CONC_N * 4);
  float* sl_ic  = (float*)alloc(ITEM_N * 4);
  float* sr_ic  = (float*)alloc(CONC_N * 4);
  float* sl_ci  = (float*)alloc(CONC_N * 4);
  float* sr_ci  = (float*)alloc(ITEM_N * 4);
  float* sl_si  = (float*)alloc(STU_N * 4);
  float* sr_si  = (float*)alloc(ITEM_N * 4);
  float* sl_is  = (float*)alloc(ITEM_N * 4);
  float* sr_is  = (float*)alloc(STU_N * 4);
  float* sl_cce = (float*)alloc(CONC_N * 4);
  float* sr_cce = (float*)alloc(CONC_N * 4);
  float* sl_ice = (float*)alloc(CONC_N * 4);
  float* sr_ice = (float*)alloc(CONC_N * 4);

  unsigned* keys0 = (unsigned*)alloc((size_t)NE_CC * 4);
  unsigned* keys1 = (unsigned*)alloc((size_t)NE_IC * 4);
  unsigned* keys2 = (unsigned*)alloc((size_t)NE_IC * 4);
  unsigned* keys3 = (unsigned*)alloc((size_t)NE_SI * 4);
  unsigned* keys4 = (unsigned*)alloc((size_t)NE_SI * 4);
  int* srcs0 = (int*)alloc((size_t)NE_CC * 4);
  int* srcs1 = (int*)alloc((size_t)NE_IC * 4);
  int* srcs2 = (int*)alloc((size_t)NE_IC * 4);
  int* srcs3 = (int*)alloc((size_t)NE_SI * 4);
  int* srcs4 = (int*)alloc((size_t)NE_SI * 4);
  int* offs0 = (int*)alloc((CONC_N + 1) * 4);
  int* offs1 = (int*)alloc((CONC_N + 1) * 4);
  int* offs2 = (int*)alloc((ITEM_N + 1) * 4);
  int* offs3 = (int*)alloc((ITEM_N + 1) * 4);
  int* offs4 = (int*)alloc((STU_N + 1) * 4);
  int* pcnt      = (int*)alloc(5 * 32 * 128 * 4);
  int* cur_all   = (int*)alloc(TBUCK * 4);
  int* bases_all = (int*)alloc((TBUCK + 5) * 4);

  float* out = (float*)d_out;
  float* out_conc = out;
  float* out_item = out + (size_t)CONC_N * 128;
  float* out_stu  = out + (size_t)(CONC_N + ITEM_N) * 128;

  CsrGs G;
  G.g[0] = {cc_dst,  cc_src,  keys0, srcs0, offs0, NE_CC, CONC_N, 5, 63,   0,   0};
  G.g[1] = {ic_conc, ic_item, keys1, srcs1, offs1, NE_IC, CONC_N, 5, 63,  63,  64};
  G.g[2] = {ic_item, ic_conc, keys2, srcs2, offs2, NE_IC, ITEM_N, 8, 79, 126, 128};
  G.g[3] = {si_item, si_stu,  keys3, srcs3, offs3, NE_SI, ITEM_N, 8, 79, 205, 208};
  G.g[4] = {si_stu,  si_item, keys4, srcs4, offs4, NE_SI, STU_N,  9, 98, 284, 288};

  // 1) setup: proj vectors + per-block CSR histograms + W->bf16
  SetupArgs SA;
  SA.p[0] = {W_cc, al_cc, vecs + 0 * 128};
  SA.p[1] = {W_cc, ar_cc, vecs + 1 * 128};
  SA.p[2] = {W_ic, al_ic, vecs + 2 * 128};
  SA.p[3] = {W_ic, ar_ic, vecs + 3 * 128};
  SA.p[4] = {W_ci, al_ci, vecs + 4 * 128};
  SA.p[5] = {W_ci, ar_ci, vecs + 5 * 128};
  SA.p[6] = {W_si, al_si, vecs + 6 * 128};
  SA.p[7] = {W_si, ar_si, vecs + 7 * 128};
  SA.p[8] = {W_is, al_is, vecs + 8 * 128};
  SA.p[9] = {W_is, ar_is, vecs + 9 * 128};
  SA.G = G;
  SA.pcnt = pcnt;
  SA.wsrc[0] = W_cc; SA.wsrc[1] = W_ic; SA.wsrc[2] = W_ci;
  SA.wsrc[3] = W_si; SA.wsrc[4] = W_is;
  for (int i = 0; i < 5; ++i) SA.wdst[i] = Wbf[i];
  setup_k<<<175, 256, 0, stream>>>(SA);

  // 2-4) CSR build
  csr_scan<<<1, 512, 0, stream>>>(G, pcnt, cur_all, bases_all);
  csr_partition<<<dim3(120, 5), 256, 0, stream>>>(G, cur_all);
  csr_build<<<TBUCK, 256, 0, stream>>>(G, bases_all);

  // 5) batched MFMA linear transforms + score dots
  BigC C;
  C.g[0] = {conc_x, concWcc, CONC_N, 0};
  C.g[1] = {item_x, itemWic, ITEM_N, 32};
  C.g[2] = {conc_x, concWci, CONC_N, 345};
  C.g[3] = {stu_x,  stuWsi,  STU_N,  377};
  C.g[4] = {item_x, itemWis, ITEM_N, 1159};
  C.gemm_blocks = 1472;
  C.m[0] = {conc_x, {vecs + 0 * 128, vecs + 1 * 128, vecs + 3 * 128, vecs + 4 * 128, ar_cce, ar_ice},
            {sl_cc, sr_cc, sr_ic, sl_ci, sr_cce, sr_ice}, CONC_N, 6, 1472, 16};
  C.m[1] = {item_x, {vecs + 2 * 128, vecs + 5 * 128, vecs + 7 * 128, vecs + 8 * 128, nullptr, nullptr},
            {sl_ic, sr_ci, sr_si, sl_is, nullptr, nullptr}, ITEM_N, 4, 1488, 64};
  C.m[2] = {stu_x, {vecs + 6 * 128, nullptr, nullptr, nullptr, nullptr, nullptr},
            {sl_si, nullptr, nullptr, nullptr, nullptr, nullptr}, STU_N, 1, 1552, 128};
  C.m[3] = {stu_raw_x, {vecs + 9 * 128, nullptr, nullptr, nullptr, nullptr, nullptr},
            {sr_is, nullptr, nullptr, nullptr, nullptr, nullptr}, STU_N, 1, 1680, 128};
  big_compute<<<1808, 256, 0, stream>>>(C, Wbf[0], Wbf[1], Wbf[2], Wbf[3], Wbf[4]);

  // 6) c1 + c2 with fused epilogue dots
  gat_c1c2<<<dim3((CONC_N + 3) / 4, 2), 256, 0, stream>>>(
      offs0, srcs0, sl_cc, sr_cc, (const uint*)concWcc, al_cce, c1buf, sl_cce,
      offs1, srcs1, sl_ic, sr_ic, (const uint*)itemWic, al_ice, c2buf, sl_ice,
      CONC_N);

  // 7) conc_fused = conc_x + e1 + e2
  gat_agg_dual<<<(CONC_N + 3) / 4, 256, 0, stream>>>(
      offs0, srcs0, sl_cce, sr_cce, c1buf, sl_ice, sr_ice, c2buf,
      conc_x, out_conc, CONC_N);

  // 8) i1 -> out_item = item_x + i1
  gat_agg_bf<<<(ITEM_N + 3) / 4, 256, 0, stream>>>(offs2, srcs2, sl_ci, sr_ci,
                                                   (const uint*)concWci, item_x, out_item, ITEM_N);
  // 9) i2 -> out_item += i2 (in-place base)
  gat_agg_bf<<<(ITEM_N + 3) / 4, 256, 0, stream>>>(offs3, srcs3, sl_si, sr_si,
                                                   (const uint*)stuWsi, out_item, out_item, ITEM_N);

  // 10) s1 -> out_stu = stu_raw_x + s1
  gat_agg_bf<<<(STU_N + 3) / 4, 256, 0, stream>>>(offs4, srcs4, sl_is, sr_is,
                                                  (const uint*)itemWis, stu_raw_x, out_stu, STU_N);
}

// Round 8
// 225.989 us; speedup vs baseline: 1.6285x; 1.6285x over previous
//
#include <hip/hip_runtime.h>

#define CONC_N 2000
#define ITEM_N 20000
#define STU_N  50000
#define NE_CC  40000
#define NE_IC  80000
#define NE_SI  1000000
#define TBUCK  382   // 63+63+79+79+98

typedef unsigned int uint;
typedef unsigned short ushort;
typedef __attribute__((ext_vector_type(8))) short bf16x8;
typedef __attribute__((ext_vector_type(4))) float f32x4;

__device__ __forceinline__ ushort f2bf(float f) {
  uint u = __float_as_uint(f);
  uint r = (u + 0x7FFFu + ((u >> 16) & 1u)) >> 16;
  return (ushort)r;
}

__device__ __forceinline__ bf16x8 packfrag(float4 lo, float4 hi) {
  union { bf16x8 s; uint u[4]; } p;
  p.u[0] = (uint)f2bf(lo.x) | ((uint)f2bf(lo.y) << 16);
  p.u[1] = (uint)f2bf(lo.z) | ((uint)f2bf(lo.w) << 16);
  p.u[2] = (uint)f2bf(hi.x) | ((uint)f2bf(hi.y) << 16);
  p.u[3] = (uint)f2bf(hi.z) | ((uint)f2bf(hi.w) << 16);
  return p.s;
}

// ---------------- CSR structures ----------------

struct CsrG {
  const int* dst; const int* src;
  unsigned* keys; int* srcs; int* offs;
  int E, n, shift, nbuck, tb, sb;
};
struct CsrGs { CsrG g[5]; };

// ------- setup: proj vectors (LDS-staged) + CSR histograms + W->frag-bf16 --

struct ProjDesc { const float* W; const float* a; float* out; };
struct SetupArgs {
  ProjDesc p[10];
  CsrGs G;
  int* pcnt;                 // [5*32][128]
  const float* wsrc[5];
  ushort* wdst[5];           // fragment-ordered bf16, 2048 recs x 16B
};

__global__ __launch_bounds__(256) void setup_k(SetupArgs A) {
  int b = blockIdx.x;
  int tid = threadIdx.x;
  if (b < 10) {              // proj: out = W^T a, LDS-staged coalesced
    __shared__ float Wl[128 * 132];
    __shared__ float a_s[128];
    ProjDesc d = A.p[b];
    #pragma unroll
    for (int i = 0; i < 16; ++i) {
      int s = tid + i * 256;           // float4 index 0..4095
      int row = s >> 5, c4 = s & 31;
      float4 w = *(const float4*)&d.W[s * 4];
      float* dst = &Wl[row * 132 + c4 * 4];
      dst[0] = w.x; dst[1] = w.y; dst[2] = w.z; dst[3] = w.w;
    }
    if (tid < 128) a_s[tid] = d.a[tid];
    __syncthreads();
    if (tid < 128) {
      float acc = 0.f;
      #pragma unroll 4
      for (int j = 0; j < 128; ++j) acc += Wl[j * 132 + tid] * a_s[j];
      d.out[tid] = acc;
    }
    return;
  }
  if (b >= 170) {            // W fp32 -> fragment-ordered bf16
    int wi = b - 170;
    const float* Ws = A.wsrc[wi];
    ushort* Wd = A.wdst[wi];
    for (int rec = tid; rec < 2048; rec += 256) {
      int lane = rec & 63;
      int kk = (rec >> 6) & 3;
      int nt = rec >> 8;
      int x = lane & 15, g = lane >> 4;
      const float* src = &Ws[(nt * 16 + x) * 128 + kk * 32 + 4 * g];
      float4 lo = *(const float4*)src;
      float4 hi = *(const float4*)(src + 16);
      bf16x8 pk = packfrag(lo, hi);
      *(bf16x8*)&Wd[rec * 8] = pk;
    }
    return;
  }
  int bsel = b - 10;            // 0..159: histogram
  int gi = bsel >> 5, blk = bsel & 31;
  CsrG g = A.G.g[gi];
  __shared__ int lcnt[128];
  if (tid < 128) lcnt[tid] = 0;
  __syncthreads();
  int chunk = (g.E + 31) >> 5;
  int e0 = blk * chunk, e1 = min(g.E, e0 + chunk);
  for (int e = e0 + tid; e < e1; e += 256)
    atomicAdd(&lcnt[g.dst[e] >> g.shift], 1);
  __syncthreads();
  if (tid < 128) A.pcnt[bsel * 128 + tid] = lcnt[tid];
}

// ---------------- CSR scan / partition / build ----------------

__global__ __launch_bounds__(512) void csr_scan(CsrGs G, const int* __restrict__ pcnt,
                                                int* __restrict__ cur, int* __restrict__ bases) {
  __shared__ int lc[TBUCK];
  __shared__ int lb[TBUCK + 5];
  int tid = threadIdx.x, lane = tid & 63, wv = tid >> 6;
  if (tid < TBUCK) {
    int gi = 0;
    #pragma unroll
    for (int k = 1; k < 5; ++k) if (tid >= G.g[k].tb) gi = k;
    int b = tid - G.g[gi].tb;
    int s = 0;
    for (int blk = 0; blk < 32; ++blk) s += pcnt[((gi << 5) + blk) * 128 + b];
    lc[tid] = s;
  }
  __syncthreads();
  if (wv < 5) {              // one wave per graph: parallel prefix
    CsrG g = G.g[wv];
    int carry = 0;
    for (int base = 0; base < g.nbuck; base += 64) {
      int idx = base + lane;
      int v = (idx < g.nbuck) ? lc[g.tb + idx] : 0;
      int incl = v;
      #pragma unroll
      for (int o = 1; o < 64; o <<= 1) {
        int y = __shfl_up(incl, o);
        if (lane >= o) incl += y;
      }
      if (idx < g.nbuck) lb[g.sb + idx] = carry + incl - v;
      carry += __shfl(incl, 63);
    }
    if (lane == 0) lb[g.sb + g.nbuck] = carry;
  }
  __syncthreads();
  if (tid < TBUCK + 5) bases[tid] = lb[tid];
  if (tid < TBUCK) {
    int gi = 0;
    for (int k = 1; k < 5; ++k) if (tid >= G.g[k].tb) gi = k;
    cur[tid] = lb[tid + gi];
  }
  if (tid < 5) G.g[tid].offs[G.g[tid].n] = G.g[tid].E;
}

__global__ __launch_bounds__(256) void csr_partition(CsrGs G, int* __restrict__ cur) {
  CsrG g = G.g[blockIdx.y];
  __shared__ unsigned ck[4096];
  __shared__ unsigned char cb[4096];
  __shared__ int lcnt[128], lcur[128];
  int tid = threadIdx.x;
  unsigned dmask = (1u << g.shift) - 1;
  for (int c0 = blockIdx.x * 4096; c0 < g.E; c0 += gridDim.x * 4096) {
    if (tid < 128) lcnt[tid] = 0;
    __syncthreads();
    #pragma unroll
    for (int i = 0; i < 16; ++i) {
      int e = c0 + i * 256 + tid;
      if (e < g.E) {
        int d = g.dst[e], s = g.src[e];
        int b = d >> g.shift;
        ck[i * 256 + tid] = ((unsigned)(d & dmask) << 16) | (unsigned)s;
        cb[i * 256 + tid] = (unsigned char)b;
        atomicAdd(&lcnt[b], 1);
      } else cb[i * 256 + tid] = 255;
    }
    __syncthreads();
    if (tid < g.nbuck && lcnt[tid] > 0) lcur[tid] = atomicAdd(&cur[g.tb + tid], lcnt[tid]);
    __syncthreads();
    #pragma unroll
    for (int i = 0; i < 16; ++i) {
      int b = cb[i * 256 + tid];
      if (b != 255) {
        int pos = atomicAdd(&lcur[b], 1);
        g.keys[pos] = ck[i * 256 + tid];
      }
    }
    __syncthreads();
  }
}

__global__ __launch_bounds__(256) void csr_build(CsrGs G, const int* __restrict__ bases) {
  int bid = blockIdx.x;
  int gi = 0;
  for (int k = 1; k < 5; ++k) if (bid >= G.g[k].tb) gi = k;
  CsrG g = G.g[gi];
  int b = bid - g.tb;
  int base = bases[g.sb + b];
  int cnt = bases[g.sb + b + 1] - base;
  if (cnt > 16384) cnt = 16384;

  __shared__ unsigned lkeys[16384];
  __shared__ int lh[512], lex[512], lcu[512], wsum[4];
  int tid = threadIdx.x;
  lh[tid] = 0; lh[tid + 256] = 0;
  __syncthreads();
  for (int j = tid; j < cnt; j += 256) {
    unsigned k = g.keys[base + j];
    lkeys[j] = k;
    atomicAdd(&lh[k >> 16], 1);
  }
  __syncthreads();
  int a0 = lh[2 * tid], a1 = lh[2 * tid + 1];
  int pair = a0 + a1;
  int lane = tid & 63, wv = tid >> 6;
  int incl = pair;
  #pragma unroll
  for (int o = 1; o < 64; o <<= 1) {
    int y = __shfl_up(incl, o);
    if (lane >= o) incl += y;
  }
  if (lane == 63) wsum[wv] = incl;
  __syncthreads();
  if (tid == 0) {
    int s = 0;
    #pragma unroll
    for (int w = 0; w < 4; ++w) { int t = wsum[w]; wsum[w] = s; s += t; }
  }
  __syncthreads();
  int ep = wsum[wv] + incl - pair;
  lex[2 * tid] = ep;       lex[2 * tid + 1] = ep + a0;
  lcu[2 * tid] = ep;       lcu[2 * tid + 1] = ep + a0;
  __syncthreads();
  int dst0 = b << g.shift;
  int ndst = min(1 << g.shift, g.n - dst0);
  for (int dl = tid; dl < ndst; dl += 256) g.offs[dst0 + dl] = base + lex[dl];
  for (int j = tid; j < cnt; j += 256) {
    unsigned k = lkeys[j];
    int dl = k >> 16;
    int pos = atomicAdd(&lcu[dl], 1);
    g.srcs[base + pos] = (int)(k & 0xFFFFu);
  }
}

// ------------- batched MFMA GEMM (+fused score dots) + stu_raw dot --------

struct GemmDesc { const float* X; ushort* Y; int n, b0; const float* dv[6]; float* dq[6]; };
struct BigC {
  GemmDesc g[5];
  int gemm_blocks;
  const float* rx; const float* rv; float* ro; int rnb;   // stu_raw dot
};

template <int NV>
__device__ void gemm_bodyT(const GemmDesc& gd, const ushort* __restrict__ Wf, int blk) {
  int tid = threadIdx.x;
  int lane = tid & 63, wv = tid >> 6;
  int x = lane & 15, g = lane >> 4;
  int row = blk * 64 + wv * 16 + x;
  const float* xr = &gd.X[(size_t)(row < gd.n ? row : 0) * 128];
  bf16x8 afrag[4];
  float dacc[NV == 0 ? 1 : NV];
  #pragma unroll
  for (int v = 0; v < NV; ++v) dacc[v] = 0.f;
  #pragma unroll
  for (int kk = 0; kk < 4; ++kk) {
    float4 lo = *(const float4*)&xr[kk * 32 + 4 * g];
    float4 hi = *(const float4*)&xr[kk * 32 + 16 + 4 * g];
    afrag[kk] = packfrag(lo, hi);
    #pragma unroll
    for (int v = 0; v < NV; ++v) {
      const float* vp = gd.dv[v];
      float4 vlo = *(const float4*)&vp[kk * 32 + 4 * g];
      float4 vhi = *(const float4*)&vp[kk * 32 + 16 + 4 * g];
      dacc[v] += lo.x * vlo.x + lo.y * vlo.y + lo.z * vlo.z + lo.w * vlo.w
               + hi.x * vhi.x + hi.y * vhi.y + hi.z * vhi.z + hi.w * vhi.w;
    }
  }
  #pragma unroll
  for (int v = 0; v < NV; ++v) {
    float dsum = dacc[v];
    dsum += __shfl_xor(dsum, 16);
    dsum += __shfl_xor(dsum, 32);
    if (lane < 16 && row < gd.n) gd.dq[v][row] = dsum;
  }
  f32x4 acc[8];
  #pragma unroll
  for (int t = 0; t < 8; ++t) acc[t] = (f32x4){0.f, 0.f, 0.f, 0.f};
  #pragma unroll
  for (int nt = 0; nt < 8; ++nt) {
    #pragma unroll
    for (int kk = 0; kk < 4; ++kk) {
      union { uint4 u; bf16x8 s; } bu;
      bu.u = *(const uint4*)&Wf[(size_t)((nt * 4 + kk) * 64 + lane) * 8];
      acc[nt] = __builtin_amdgcn_mfma_f32_16x16x32_bf16(afrag[kk], bu.s, acc[nt], 0, 0, 0);
    }
  }
  // D layout: col = lane&15, row = (lane>>4)*4 + r
  int orow = blk * 64 + wv * 16 + 4 * g;
  #pragma unroll
  for (int r = 0; r < 4; ++r) {
    int gr = orow + r;
    if (gr < gd.n) {
      #pragma unroll
      for (int nt = 0; nt < 8; ++nt)
        gd.Y[(size_t)gr * 128 + nt * 16 + x] = f2bf(acc[nt][r]);
    }
  }
}

__device__ void rdot_body(const float* __restrict__ x, const float* __restrict__ v,
                          float* __restrict__ o, int n, int blk, int nblk) {
  int lane = threadIdx.x & 63;
  int wid = (blk * 256 + threadIdx.x) >> 6;
  int nw = nblk * 4;
  float va = v[lane], vb = v[64 + lane];
  for (int r = wid; r < n; r += nw) {
    float a = x[r * 128 + lane] * va + x[r * 128 + 64 + lane] * vb;
    #pragma unroll
    for (int of = 32; of; of >>= 1) a += __shfl_xor(a, of);
    if (lane == 0) o[r] = a;
  }
}

__global__ __launch_bounds__(256, 2) void big_compute(BigC C, const ushort* W0,
                                                      const ushort* W1, const ushort* W2,
                                                      const ushort* W3, const ushort* W4) {
  int b = blockIdx.x;
  if (b < C.gemm_blocks) {
    if (b < C.g[1].b0)      gemm_bodyT<6>(C.g[0], W0, b - C.g[0].b0);
    else if (b < C.g[2].b0) gemm_bodyT<4>(C.g[1], W1, b - C.g[1].b0);
    else if (b < C.g[3].b0) gemm_bodyT<0>(C.g[2], W2, b - C.g[2].b0);
    else if (b < C.g[4].b0) gemm_bodyT<1>(C.g[3], W3, b - C.g[3].b0);
    else                    gemm_bodyT<0>(C.g[4], W4, b - C.g[4].b0);
  } else {
    rdot_body(C.rx, C.rv, C.ro, STU_N, b - C.gemm_blocks, C.rnb);
  }
}

// ---------------- GAT core (wave per target, uint4 bf16 gather) ----------

__device__ void gat_core_bf(const int* __restrict__ offs, const int* __restrict__ srcs,
                            const float* __restrict__ sl, const float* __restrict__ sr,
                            const uint* __restrict__ xl, int t, int lane, float acc[8]) {
  int sbeg = offs[t], send = offs[t + 1];
  float srt = sr[t];
  int i0l = sbeg + lane;
  bool act0 = i0l < send;
  int s0 = act0 ? srcs[i0l] : 0;
  float e0;
  {
    float e = sl[s0] + srt;
    e = e > 0.f ? e : 0.2f * e;
    e0 = act0 ? e : -1e30f;
  }
  float m = e0, se = act0 ? 1.f : 0.f;
  for (int i = i0l + 64; i < send; i += 64) {
    int s = srcs[i];
    float e = sl[s] + srt;
    e = e > 0.f ? e : 0.2f * e;
    float mn = fmaxf(m, e);
    se = se * __expf(m - mn) + __expf(e - mn);
    m = mn;
  }
  #pragma unroll
  for (int o = 32; o; o >>= 1) {
    float m2 = __shfl_xor(m, o), s2 = __shfl_xor(se, o);
    float mn = fmaxf(m, m2);
    se = se * __expf(m - mn) + s2 * __expf(m2 - mn);
    m = mn;
  }
  float inv = 1.f / (se + 1e-16f);

  int g = lane & 15;
  int q = lane >> 4;
  #pragma unroll
  for (int r = 0; r < 8; ++r) acc[r] = 0.f;

  for (int i0 = sbeg; i0 < send; i0 += 64) {
    int cnt = min(64, send - i0);
    int s; float wgt;
    if (i0 == sbeg) {
      s = s0;
      wgt = act0 ? __expf(e0 - m) * inv : 0.f;
    } else {
      s = 0; wgt = 0.f;
      if (lane < cnt) {
        s = srcs[i0 + lane];
        float e = sl[s] + srt;
        e = e > 0.f ? e : 0.2f * e;
        wgt = __expf(e - m) * inv;
      }
    }
    int kmax = (cnt + 3) >> 2;
    #pragma unroll 2
    for (int k = 0; k < kmax; ++k) {
      int ej = 4 * k + q;
      int sj = __shfl(s, ej);
      float wj = __shfl(wgt, ej);
      const uint4 u = *(const uint4*)&xl[(size_t)sj * 64 + g * 4];
      acc[0] += wj * __uint_as_float(u.x << 16);
      acc[1] += wj * __uint_as_float(u.x & 0xFFFF0000u);
      acc[2] += wj * __uint_as_float(u.y << 16);
      acc[3] += wj * __uint_as_float(u.y & 0xFFFF0000u);
      acc[4] += wj * __uint_as_float(u.z << 16);
      acc[5] += wj * __uint_as_float(u.z & 0xFFFF0000u);
      acc[6] += wj * __uint_as_float(u.w << 16);
      acc[7] += wj * __uint_as_float(u.w & 0xFFFF0000u);
    }
  }
  #pragma unroll
  for (int r = 0; r < 8; ++r) {
    acc[r] += __shfl_xor(acc[r], 16);
    acc[r] += __shfl_xor(acc[r], 32);
  }
}

__device__ __forceinline__ void gat_store(const float acc[8], const float* base0,
                                          float* out, int t, int lane) {
  int g = lane & 15;
  if (lane < 16) {
    int d = t * 128 + g * 8;
    float4 a0 = make_float4(acc[0], acc[1], acc[2], acc[3]);
    float4 a1 = make_float4(acc[4], acc[5], acc[6], acc[7]);
    if (base0) {
      const float4 b0 = *(const float4*)&base0[d];
      const float4 b1 = *(const float4*)&base0[d + 4];
      a0.x += b0.x; a0.y += b0.y; a0.z += b0.z; a0.w += b0.w;
      a1.x += b1.x; a1.y += b1.y; a1.z += b1.z; a1.w += b1.w;
    }
    *(float4*)&out[d] = a0;
    *(float4*)&out[d + 4] = a1;
  }
}

// c1 + c2 batched (blockIdx.y selects), epilogue dot with al -> sl_out
__global__ void gat_c1c2(const int* __restrict__ offs0, const int* __restrict__ srcs0,
                         const float* __restrict__ sl0, const float* __restrict__ sr0,
                         const uint* __restrict__ xl0, const float* __restrict__ al0,
                         float* __restrict__ o0, float* __restrict__ slo0,
                         const int* __restrict__ offs1, const int* __restrict__ srcs1,
                         const float* __restrict__ sl1, const float* __restrict__ sr1,
                         const uint* __restrict__ xl1, const float* __restrict__ al1,
                         float* __restrict__ o1, float* __restrict__ slo1,
                         int n_tgt) {
  int t = (blockIdx.x * blockDim.x + threadIdx.x) >> 6;
  if (t >= n_tgt) return;
  int lane = threadIdx.x & 63;
  int which = blockIdx.y;
  const int* offs = which ? offs1 : offs0;
  const int* srcs = which ? srcs1 : srcs0;
  const float* sl = which ? sl1 : sl0;
  const float* sr = which ? sr1 : sr0;
  const uint* xl = which ? xl1 : xl0;
  const float* al = which ? al1 : al0;
  float* o = which ? o1 : o0;
  float* slo = which ? slo1 : slo0;

  float acc[8];
  gat_core_bf(offs, srcs, sl, sr, xl, t, lane, acc);
  int g = lane & 15;
  float4 v0 = *(const float4*)&al[g * 8];
  float4 v1 = *(const float4*)&al[g * 8 + 4];
  float p = acc[0] * v0.x + acc[1] * v0.y + acc[2] * v0.z + acc[3] * v0.w +
            acc[4] * v1.x + acc[5] * v1.y + acc[6] * v1.z + acc[7] * v1.w;
  #pragma unroll
  for (int o2 = 8; o2; o2 >>= 1) p += __shfl_xor(p, o2);
  if (lane == 0) slo[t] = p;
  if (lane < 16) {
    int d = t * 128 + g * 8;
    *(float4*)&o[d] = make_float4(acc[0], acc[1], acc[2], acc[3]);
    *(float4*)&o[d + 4] = make_float4(acc[4], acc[5], acc[6], acc[7]);
  }
}

// dual (fp32 gather of c1/c2 on cc graph) device body
__device__ void gat_dual_core(const int* __restrict__ offs, const int* __restrict__ srcs,
                              const float* __restrict__ sl1, const float* __restrict__ sr1,
                              const float* __restrict__ xl1,
                              const float* __restrict__ sl2, const float* __restrict__ sr2,
                              const float* __restrict__ xl2,
                              const float* __restrict__ base,
                              float* __restrict__ out, int t, int lane) {
  int sbeg = offs[t], send = offs[t + 1];
  float srt1 = sr1[t], srt2 = sr2[t];
  float m1 = -1e30f, m2 = -1e30f;
  for (int i = sbeg + lane; i < send; i += 64) {
    int s = srcs[i];
    float e1 = sl1[s] + srt1; e1 = e1 > 0.f ? e1 : 0.2f * e1;
    float e2 = sl2[s] + srt2; e2 = e2 > 0.f ? e2 : 0.2f * e2;
    m1 = fmaxf(m1, e1); m2 = fmaxf(m2, e2);
  }
  #pragma unroll
  for (int o = 32; o; o >>= 1) {
    m1 = fmaxf(m1, __shfl_xor(m1, o));
    m2 = fmaxf(m2, __shfl_xor(m2, o));
  }
  float se1 = 0.f, se2 = 0.f;
  for (int i = sbeg + lane; i < send; i += 64) {
    int s = srcs[i];
    float e1 = sl1[s] + srt1; e1 = e1 > 0.f ? e1 : 0.2f * e1;
    float e2 = sl2[s] + srt2; e2 = e2 > 0.f ? e2 : 0.2f * e2;
    se1 += __expf(e1 - m1); se2 += __expf(e2 - m2);
  }
  #pragma unroll
  for (int o = 32; o; o >>= 1) {
    se1 += __shfl_xor(se1, o);
    se2 += __shfl_xor(se2, o);
  }
  float inv1 = 1.f / (se1 + 1e-16f), inv2 = 1.f / (se2 + 1e-16f);
  float ax = 0.f, ay = 0.f;
  for (int i0 = sbeg; i0 < send; i0 += 64) {
    int cnt = min(64, send - i0);
    int s = 0; float w1 = 0.f, w2 = 0.f;
    if (lane < cnt) {
      s = srcs[i0 + lane];
      float e1 = sl1[s] + srt1; e1 = e1 > 0.f ? e1 : 0.2f * e1;
      float e2 = sl2[s] + srt2; e2 = e2 > 0.f ? e2 : 0.2f * e2;
      w1 = __expf(e1 - m1) * inv1;
      w2 = __expf(e2 - m2) * inv2;
    }
    for (int j = 0; j < cnt; ++j) {
      int sj = __shfl(s, j);
      float wj1 = __shfl(w1, j);
      float wj2 = __shfl(w2, j);
      const float2 v1 = *(const float2*)&xl1[sj * 128 + lane * 2];
      const float2 v2 = *(const float2*)&xl2[sj * 128 + lane * 2];
      ax += wj1 * v1.x + wj2 * v2.x;
      ay += wj1 * v1.y + wj2 * v2.y;
    }
  }
  const float2 b = *(const float2*)&base[t * 128 + lane * 2];
  float2 o2; o2.x = ax + b.x; o2.y = ay + b.y;
  *(float2*)&out[t * 128 + lane * 2] = o2;
}

// merged: [dual(conc)] + [i1(item)]
__global__ void gat_dual_i1(const int* offsD, const int* srcsD,
                            const float* sl1, const float* sr1, const float* xl1,
                            const float* sl2, const float* sr2, const float* xl2,
                            const float* baseD, float* outD, int nD, int nblkD,
                            const int* offsI, const int* srcsI,
                            const float* slI, const float* srI, const uint* xlI,
                            const float* baseI, float* outI, int nI) {
  int b = blockIdx.x;
  int lane = threadIdx.x & 63;
  if (b < nblkD) {
    int t = (b * blockDim.x + threadIdx.x) >> 6;
    if (t >= nD) return;
    gat_dual_core(offsD, srcsD, sl1, sr1, xl1, sl2, sr2, xl2, baseD, outD, t, lane);
  } else {
    int t = ((b - nblkD) * blockDim.x + threadIdx.x) >> 6;
    if (t >= nI) return;
    float acc[8];
    gat_core_bf(offsI, srcsI, slI, srI, xlI, t, lane, acc);
    gat_store(acc, baseI, outI, t, lane);
  }
}

// merged: [i2(item, in-place)] + [s1(stu)]
__global__ void gat_two_bf(const int* offsA, const int* srcsA,
                           const float* slA, const float* srA, const uint* xlA,
                           const float* baseA, float* outA, int nA, int nblkA,
                           const int* offsB, const int* srcsB,
                           const float* slB, const float* srB, const uint* xlB,
                           const float* baseB, float* outB, int nB) {
  int b = blockIdx.x;
  int lane = threadIdx.x & 63;
  if (b < nblkA) {
    int t = (b * blockDim.x + threadIdx.x) >> 6;
    if (t >= nA) return;
    float acc[8];
    gat_core_bf(offsA, srcsA, slA, srA, xlA, t, lane, acc);
    gat_store(acc, baseA, outA, t, lane);
  } else {
    int t = ((b - nblkA) * blockDim.x + threadIdx.x) >> 6;
    if (t >= nB) return;
    float acc[8];
    gat_core_bf(offsB, srcsB, slB, srB, xlB, t, lane, acc);
    gat_store(acc, baseB, outB, t, lane);
  }
}

// ---------------- launch ----------------

extern "C" void kernel_launch(void* const* d_in, const int* in_sizes, int n_in,
                              void* d_out, int out_size, void* d_ws, size_t ws_size,
                              hipStream_t stream) {
  const float* stu_x     = (const float*)d_in[0];
  const float* item_x    = (const float*)d_in[1];
  const float* conc_x    = (const float*)d_in[2];
  const float* stu_raw_x = (const float*)d_in[3];
  const float* W_cc  = (const float*)d_in[4];
  const float* al_cc = (const float*)d_in[5];
  const float* ar_cc = (const float*)d_in[6];
  const float* W_ic  = (const float*)d_in[7];
  const float* al_ic = (const float*)d_in[8];
  const float* ar_ic = (const float*)d_in[9];
  const float* al_cce = (const float*)d_in[10];
  const float* ar_cce = (const float*)d_in[11];
  const float* al_ice = (const float*)d_in[12];
  const float* ar_ice = (const float*)d_in[13];
  const float* W_ci  = (const float*)d_in[14];
  const float* al_ci = (const float*)d_in[15];
  const float* ar_ci = (const float*)d_in[16];
  const float* W_si  = (const float*)d_in[17];
  const float* al_si = (const float*)d_in[18];
  const float* ar_si = (const float*)d_in[19];
  const float* W_is  = (const float*)d_in[22];
  const float* al_is = (const float*)d_in[23];
  const float* ar_is = (const float*)d_in[24];
  const int* cc_src  = (const int*)d_in[25];
  const int* cc_dst  = (const int*)d_in[26];
  const int* ic_item = (const int*)d_in[27];
  const int* ic_conc = (const int*)d_in[28];
  const int* si_stu  = (const int*)d_in[29];
  const int* si_item = (const int*)d_in[30];

  char* wsb = (char*)d_ws;
  size_t off = 0;
  auto alloc = [&](size_t bytes) -> void* {
    void* p = wsb + off;
    off = (off + bytes + 255) & ~(size_t)255;
    return p;
  };

  ushort* concWcc = (ushort*)alloc((size_t)CONC_N * 128 * 2);
  ushort* itemWic = (ushort*)alloc((size_t)ITEM_N * 128 * 2);
  ushort* concWci = (ushort*)alloc((size_t)CONC_N * 128 * 2);
  ushort* stuWsi  = (ushort*)alloc((size_t)STU_N  * 128 * 2);
  ushort* itemWis = (ushort*)alloc((size_t)ITEM_N * 128 * 2);
  ushort* Wbf[5];
  for (int i = 0; i < 5; ++i) Wbf[i] = (ushort*)alloc(128 * 128 * 2);
  float* c1buf   = (float*)alloc((size_t)CONC_N * 128 * 4);
  float* c2buf   = (float*)alloc((size_t)CONC_N * 128 * 4);
  float* vecs    = (float*)alloc(10 * 128 * 4);
  float* sl_cc  = (float*)alloc(CONC_N * 4);
  float* sr_cc  = (float*)alloc(CONC_N * 4);
  float* sl_ic  = (float*)alloc(ITEM_N * 4);
  float* sr_ic  = (float*)alloc(CONC_N * 4);
  float* sl_ci  = (float*)alloc(CONC_N * 4);
  float* sr_ci  = (float*)alloc(ITEM_N * 4);
  float* sl_si  = (float*)alloc(STU_N * 4);
  float* sr_si  = (float*)alloc(ITEM_N * 4);
  float* sl_is  = (float*)alloc(ITEM_N * 4);
  float* sr_is  = (float*)alloc(STU_N * 4);
  float* sl_cce = (float*)alloc(CONC_N * 4);
  float* sr_cce = (float*)alloc(CONC_N * 4);
  float* sl_ice = (float*)alloc(CONC_N * 4);
  float* sr_ice = (float*)alloc(CONC_N * 4);

  unsigned* keys0 = (unsigned*)alloc((size_t)NE_CC * 4);
  unsigned* keys1 = (unsigned*)alloc((size_t)NE_IC * 4);
  unsigned* keys2 = (unsigned*)alloc((size_t)NE_IC * 4);
  unsigned* keys3 = (unsigned*)alloc((size_t)NE_SI * 4);
  unsigned* keys4 = (unsigned*)alloc((size_t)NE_SI * 4);
  int* srcs0 = (int*)alloc((size_t)NE_CC * 4);
  int* srcs1 = (int*)alloc((size_t)NE_IC * 4);
  int* srcs2 = (int*)alloc((size_t)NE_IC * 4);
  int* srcs3 = (int*)alloc((size_t)NE_SI * 4);
  int* srcs4 = (int*)alloc((size_t)NE_SI * 4);
  int* offs0 = (int*)alloc((CONC_N + 1) * 4);
  int* offs1 = (int*)alloc((CONC_N + 1) * 4);
  int* offs2 = (int*)alloc((ITEM_N + 1) * 4);
  int* offs3 = (int*)alloc((ITEM_N + 1) * 4);
  int* offs4 = (int*)alloc((STU_N + 1) * 4);
  int* pcnt      = (int*)alloc(5 * 32 * 128 * 4);
  int* cur_all   = (int*)alloc(TBUCK * 4);
  int* bases_all = (int*)alloc((TBUCK + 5) * 4);

  float* out = (float*)d_out;
  float* out_conc = out;
  float* out_item = out + (size_t)CONC_N * 128;
  float* out_stu  = out + (size_t)(CONC_N + ITEM_N) * 128;

  CsrGs G;
  G.g[0] = {cc_dst,  cc_src,  keys0, srcs0, offs0, NE_CC, CONC_N, 5, 63,   0,   0};
  G.g[1] = {ic_conc, ic_item, keys1, srcs1, offs1, NE_IC, CONC_N, 5, 63,  63,  64};
  G.g[2] = {ic_item, ic_conc, keys2, srcs2, offs2, NE_IC, ITEM_N, 8, 79, 126, 128};
  G.g[3] = {si_item, si_stu,  keys3, srcs3, offs3, NE_SI, ITEM_N, 8, 79, 205, 208};
  G.g[4] = {si_stu,  si_item, keys4, srcs4, offs4, NE_SI, STU_N,  9, 98, 284, 288};

  // 1) setup: proj vectors + CSR histograms + W->frag-bf16
  SetupArgs SA;
  SA.p[0] = {W_cc, al_cc, vecs + 0 * 128};
  SA.p[1] = {W_cc, ar_cc, vecs + 1 * 128};
  SA.p[2] = {W_ic, al_ic, vecs + 2 * 128};
  SA.p[3] = {W_ic, ar_ic, vecs + 3 * 128};
  SA.p[4] = {W_ci, al_ci, vecs + 4 * 128};
  SA.p[5] = {W_ci, ar_ci, vecs + 5 * 128};
  SA.p[6] = {W_si, al_si, vecs + 6 * 128};
  SA.p[7] = {W_si, ar_si, vecs + 7 * 128};
  SA.p[8] = {W_is, al_is, vecs + 8 * 128};
  SA.p[9] = {W_is, ar_is, vecs + 9 * 128};
  SA.G = G;
  SA.pcnt = pcnt;
  SA.wsrc[0] = W_cc; SA.wsrc[1] = W_ic; SA.wsrc[2] = W_ci;
  SA.wsrc[3] = W_si; SA.wsrc[4] = W_is;
  for (int i = 0; i < 5; ++i) SA.wdst[i] = Wbf[i];
  setup_k<<<175, 256, 0, stream>>>(SA);

  // 2-4) CSR build
  csr_scan<<<1, 512, 0, stream>>>(G, pcnt, cur_all, bases_all);
  csr_partition<<<dim3(120, 5), 256, 0, stream>>>(G, cur_all);
  csr_build<<<TBUCK, 256, 0, stream>>>(G, bases_all);

  // 5) batched MFMA gemms (+fused score dots) + stu_raw dot
  BigC C;
  C.g[0] = {conc_x, concWcc, CONC_N, 0,
            {vecs + 0 * 128, vecs + 1 * 128, vecs + 3 * 128, vecs + 4 * 128, ar_cce, ar_ice},
            {sl_cc, sr_cc, sr_ic, sl_ci, sr_cce, sr_ice}};
  C.g[1] = {item_x, itemWic, ITEM_N, 32,
            {vecs + 2 * 128, vecs + 5 * 128, vecs + 7 * 128, vecs + 8 * 128, nullptr, nullptr},
            {sl_ic, sr_ci, sr_si, sl_is, nullptr, nullptr}};
  C.g[2] = {conc_x, concWci, CONC_N, 345,
            {nullptr, nullptr, nullptr, nullptr, nullptr, nullptr},
            {nullptr, nullptr, nullptr, nullptr, nullptr, nullptr}};
  C.g[3] = {stu_x, stuWsi, STU_N, 377,
            {vecs + 6 * 128, nullptr, nullptr, nullptr, nullptr, nullptr},
            {sl_si, nullptr, nullptr, nullptr, nullptr, nullptr}};
  C.g[4] = {item_x, itemWis, ITEM_N, 1159,
            {nullptr, nullptr, nullptr, nullptr, nullptr, nullptr},
            {nullptr, nullptr, nullptr, nullptr, nullptr, nullptr}};
  C.gemm_blocks = 1472;
  C.rx = stu_raw_x; C.rv = vecs + 9 * 128; C.ro = sr_is; C.rnb = 1024;
  big_compute<<<2496, 256, 0, stream>>>(C, Wbf[0], Wbf[1], Wbf[2], Wbf[3], Wbf[4]);

  // 6) c1 + c2 with fused epilogue dots
  gat_c1c2<<<dim3((CONC_N + 3) / 4, 2), 256, 0, stream>>>(
      offs0, srcs0, sl_cc, sr_cc, (const uint*)concWcc, al_cce, c1buf, sl_cce,
      offs1, srcs1, sl_ic, sr_ic, (const uint*)itemWic, al_ice, c2buf, sl_ice,
      CONC_N);

  // 7) [conc_fused dual] + [i1 -> out_item = item_x + i1]
  gat_dual_i1<<<500 + 5000, 256, 0, stream>>>(
      offs0, srcs0, sl_cce, sr_cce, c1buf, sl_ice, sr_ice, c2buf,
      conc_x, out_conc, CONC_N, 500,
      offs2, srcs2, sl_ci, sr_ci, (const uint*)concWci, item_x, out_item, ITEM_N);

  // 8) [i2 -> out_item += i2] + [s1 -> out_stu = stu_raw_x + s1]
  gat_two_bf<<<5000 + 12500, 256, 0, stream>>>(
      offs3, srcs3, sl_si, sr_si, (const uint*)stuWsi, out_item, out_item, ITEM_N, 5000,
      offs4, srcs4, sl_is, sr_is, (const uint*)itemWis, stu_raw_x, out_stu, STU_N);
}